// Round 8
// baseline (172.521 us; speedup 1.0000x reference)
//
#include <hip/hip_runtime.h>
#include <hip/hip_bf16.h>
#include <cstdint>

#define NHEAD 16
#define ORDERS 4

typedef short short8 __attribute__((ext_vector_type(8)));
typedef float f32x4 __attribute__((ext_vector_type(4)));

__device__ __forceinline__ unsigned short f32_to_bf16_rtn(float f) {
  union { float f; unsigned u; } v; v.f = f;
  unsigned r = v.u + 0x7FFFu + ((v.u >> 16) & 1u);
  return (unsigned short)(r >> 16);
}

typedef __attribute__((address_space(1))) void gvoid;
typedef __attribute__((address_space(3))) void svoid;
__device__ __forceinline__ void gload_lds16(const void* g, void* l) {
  // LDS dest = base + lane*16 (wave-uniform base); global src is per-lane
  __builtin_amdgcn_global_load_lds((gvoid*)g, (svoid*)l, 16, 0, 0);
}

// ====== weff kernel: block (h, 64-col chunk c) computes M_h then W_eff ======
__global__ __launch_bounds__(256) void weff_kernel(
    const float* __restrict__ A, const float* __restrict__ t_ptr,
    const float* __restrict__ W, const float* __restrict__ bvec,
    unsigned short* __restrict__ Weff, float* __restrict__ beff) {
  __shared__ float Ah[64 * 65];  // reused as Mh (stride 64) after the orders
  __shared__ float T0[64 * 64];
  __shared__ float T1[64 * 64];

  const int tid = threadIdx.x;
  const int h = blockIdx.x >> 4;
  const int c = blockIdx.x & 15;
  const int d = tid & 63;
  const int ig = tid >> 6;

  float wreg[16];
  #pragma unroll
  for (int r = 0; r < 16; ++r)
    wreg[r] = W[(size_t)(h * 64 + ig * 16 + r) * 1024 + c * 64 + d];

  const float t = t_ptr[0];
  const int i = tid >> 2;
  const int jq = (tid & 3) << 4;

  for (int r = 0; r < 16; ++r) {
    int idx = tid + 256 * r;
    Ah[(idx >> 6) * 65 + (idx & 63)] = A[h * 4096 + idx];
  }
  float ms[16];
  #pragma unroll
  for (int cc = 0; cc < 16; ++cc) {
    float e = (i == jq + cc) ? 1.0f : 0.0f;
    T0[i * 64 + jq + cc] = e;
    ms[cc] = e;
  }
  __syncthreads();

  float* Tc = T0;
  float* Tn = T1;
  for (int k = 1; k <= ORDERS; ++k) {
    float scale = t / (float)k;
    float acc[16];
    #pragma unroll
    for (int cc = 0; cc < 16; ++cc) acc[cc] = 0.f;
    for (int l = 0; l < 64; ++l) {
      float a = Ah[i * 65 + l];
      float4 t0 = *(const float4*)&Tc[l * 64 + jq];
      float4 t1 = *(const float4*)&Tc[l * 64 + jq + 4];
      float4 t2 = *(const float4*)&Tc[l * 64 + jq + 8];
      float4 t3 = *(const float4*)&Tc[l * 64 + jq + 12];
      acc[0] += a * t0.x;  acc[1] += a * t0.y;  acc[2] += a * t0.z;  acc[3] += a * t0.w;
      acc[4] += a * t1.x;  acc[5] += a * t1.y;  acc[6] += a * t1.z;  acc[7] += a * t1.w;
      acc[8] += a * t2.x;  acc[9] += a * t2.y;  acc[10] += a * t2.z; acc[11] += a * t2.w;
      acc[12] += a * t3.x; acc[13] += a * t3.y; acc[14] += a * t3.z; acc[15] += a * t3.w;
    }
    #pragma unroll
    for (int cc = 0; cc < 16; ++cc) { acc[cc] *= scale; ms[cc] += acc[cc]; }
    #pragma unroll
    for (int u = 0; u < 4; ++u) {
      float4 v = {acc[u * 4], acc[u * 4 + 1], acc[u * 4 + 2], acc[u * 4 + 3]};
      *(float4*)&Tn[i * 64 + jq + u * 4] = v;
    }
    __syncthreads();
    float* tmp = Tc; Tc = Tn; Tn = tmp;
  }

  float* Mh = Ah;
  #pragma unroll
  for (int u = 0; u < 4; ++u) {
    float4 v = {ms[u * 4], ms[u * 4 + 1], ms[u * 4 + 2], ms[u * 4 + 3]};
    *(float4*)&Mh[i * 64 + jq + u * 4] = v;
  }
  float* Wc = T0;
  #pragma unroll
  for (int r = 0; r < 16; ++r) Wc[(ig * 16 + r) * 64 + d] = wreg[r];
  __syncthreads();

  #pragma unroll
  for (int ii = 0; ii < 16; ++ii) {
    int i2 = ig * 16 + ii;
    float acc = 0.f;
    #pragma unroll
    for (int j = 0; j < 64; ++j) acc += Mh[i2 * 64 + j] * Wc[j * 64 + d];
    Weff[(size_t)(h * 64 + i2) * 1024 + c * 64 + d] = f32_to_bf16_rtn(acc);
  }
  if (c == 0 && tid < 64) {
    float acc = 0.f;
    for (int j = 0; j < 64; ++j) acc += Mh[tid * 64 + j] * bvec[h * 64 + j];
    beff[h * 64 + tid] = acc;
  }
}

// ------- Convert: X f32 -> bf16 Xb. No LDS -> full occupancy, BW-bound ------
__global__ __launch_bounds__(256) void convert_x_kernel(
    const float* __restrict__ X, unsigned short* __restrict__ Xb, int n8) {
  int idx = blockIdx.x * blockDim.x + threadIdx.x;
  int stride = gridDim.x * blockDim.x;
  for (int i = idx; i < n8; i += stride) {
    float4 a = *(const float4*)(X + (size_t)i * 8);
    float4 b = *(const float4*)(X + (size_t)i * 8 + 4);
    unsigned short t[8] = {f32_to_bf16_rtn(a.x), f32_to_bf16_rtn(a.y),
                           f32_to_bf16_rtn(a.z), f32_to_bf16_rtn(a.w),
                           f32_to_bf16_rtn(b.x), f32_to_bf16_rtn(b.y),
                           f32_to_bf16_rtn(b.z), f32_to_bf16_rtn(b.w)};
    *(uint4*)(Xb + (size_t)i * 8) = *(const uint4*)t;
  }
}

// ============ GEMM 256x256, 8 waves, 4-phase/K-tile deep pipeline ============
// T2 swizzle (proven involution), T3/T4 counted vmcnt(4) at tile boundary
// (placed BEFORE the closing barrier -> cross-wave completion barrier-ordered),
// T5 setprio around each 16-MFMA cluster. Staging plan (per K-tile j):
//   ph0: stage B(j+1) -> other buf (4 gloads)
//   ph1: stage A quarters {0,2} of (j+2) -> current buf (rows last read ph0)
//   ph3: stage A quarters {1,3} of (j+2) -> current buf (rows last read ph2)
// Boundary vmcnt(4) leaves only A(j+2)'s 4 loads in flight (never drains).
#define MM16(MOFF, BSET, NOFF)                                                 \
  {                                                                            \
    _Pragma("unroll") for (int m_ = 0; m_ < 4; ++m_)                           \
        _Pragma("unroll") for (int n_ = 0; n_ < 2; ++n_)                       \
            _Pragma("unroll") for (int kk_ = 0; kk_ < 2; ++kk_)                \
                acc[MOFF + m_][NOFF + n_] =                                    \
        __builtin_amdgcn_mfma_f32_16x16x32_bf16(                               \
            afr[m_][kk_], BSET[n_][kk_], acc[MOFF + m_][NOFF + n_], 0, 0, 0);  \
  }

__global__ __launch_bounds__(512, 2) void gemm256_kernel(
    const unsigned short* __restrict__ Xb, const unsigned short* __restrict__ Wf,
    const float* __restrict__ beff, float* __restrict__ Out) {
  __shared__ __align__(16) unsigned short smem[2 * 32768];  // 128 KiB

  const int wg = blockIdx.x;
  const int swz = (wg & 7) * 64 + (wg >> 3);  // 512 % 8 == 0: bijective
  const int R = (swz >> 2) * 256;
  const int C = (swz & 3) * 256;

  const int tid = threadIdx.x;
  const int lane = tid & 63;
  const int w = tid >> 6;   // 0..7
  const int wm = w >> 2;    // 0..1 -> rows [wm*128, +128)
  const int wn = w & 3;     // 0..3 -> cols [wn*64, +64)
  const int frow = lane & 15;
  const int fkg = lane >> 4;
  const int rx = frow & 7;

  // staging lane geometry (proven XOR involution, rule #21)
  const int lr = lane >> 3;
  const int scol = ((lane & 7) ^ lr) << 3;
  const unsigned short* AsrcB = Xb + (size_t)(R + w * 8 + lr) * 1024 + scol;
  const unsigned short* BsrcB = Wf + (size_t)(C + w * 8 + lr) * 1024 + scol;

  auto stageB = [&](int j) {  // all of B(j): 4 gloads -> buf[j&1] + 32KB
    char* bd = (char*)(smem + (j & 1) * 32768 + 16384) + w * 1024;
    const unsigned short* s = BsrcB + j * 64;
    #pragma unroll
    for (int g = 0; g < 4; ++g)
      gload_lds16(s + (size_t)(g * 64) * 1024, bd + g * 8192);
  };
  auto stageA = [&](int j, int half) {  // A quarters {half, half+2}: 2 gloads
    char* ad = (char*)(smem + (j & 1) * 32768) + w * 1024;
    const unsigned short* s = AsrcB + j * 64;
    #pragma unroll
    for (int g = 0; g < 2; ++g) {
      int q = half + 2 * g;
      gload_lds16(s + (size_t)(q * 64) * 1024, ad + q * 8192);
    }
  };

  f32x4 acc[8][4];
  #pragma unroll
  for (int mi = 0; mi < 8; ++mi)
    #pragma unroll
    for (int ni = 0; ni < 4; ++ni) acc[mi][ni] = (f32x4){0.f, 0.f, 0.f, 0.f};

  short8 afr[4][2], b0[2][2], b1[2][2];
  const int arow0 = wm * 128 + frow;
  const int brow0 = wn * 64 + frow;
  const int slot0 = (fkg ^ rx) << 3;
  const int slot1 = ((4 + fkg) ^ rx) << 3;

  auto rdA = [&](const unsigned short* buf, int msh) {
    #pragma unroll
    for (int m = 0; m < 4; ++m) {
      int r = (arow0 + (msh * 4 + m) * 16) * 64;
      afr[m][0] = *(const short8*)&buf[r + slot0];
      afr[m][1] = *(const short8*)&buf[r + slot1];
    }
  };
  auto rdB = [&](const unsigned short* buf, int nsh, short8 (&dst)[2][2]) {
    #pragma unroll
    for (int n = 0; n < 2; ++n) {
      int r = 16384 + (brow0 + (nsh * 2 + n) * 16) * 64;
      dst[n][0] = *(const short8*)&buf[r + slot0];
      dst[n][1] = *(const short8*)&buf[r + slot1];
    }
  };

  // Prologue: tile0 full + A(1) quarters; vmcnt(4) leaves A(1)'s 4 loads.
  stageB(0);
  stageA(0, 0);
  stageA(0, 1);
  stageA(1, 0);
  stageA(1, 1);
  asm volatile("s_waitcnt vmcnt(4)" ::: "memory");
  __builtin_amdgcn_sched_barrier(0);
  __builtin_amdgcn_s_barrier();

  for (int j = 0; j < 16; ++j) {
    const unsigned short* buf = smem + (j & 1) * 32768;

    // ---- phase 0: quadrant (msh0, nsh0); stage B(j+1) ----
    rdA(buf, 0);
    rdB(buf, 0, b0);
    if (j + 1 < 16) stageB(j + 1);
    __builtin_amdgcn_s_barrier();
    asm volatile("s_waitcnt lgkmcnt(0)" ::: "memory");
    __builtin_amdgcn_sched_barrier(0);
    __builtin_amdgcn_s_setprio(1);
    MM16(0, b0, 0);
    __builtin_amdgcn_s_setprio(0);
    __builtin_amdgcn_s_barrier();

    // ---- phase 1: (msh0, nsh1); stage A(j+2) quarters {0,2} ----
    rdB(buf, 1, b1);
    if (j + 2 < 16) stageA(j + 2, 0);
    __builtin_amdgcn_s_barrier();
    asm volatile("s_waitcnt lgkmcnt(0)" ::: "memory");
    __builtin_amdgcn_sched_barrier(0);
    __builtin_amdgcn_s_setprio(1);
    MM16(0, b1, 2);
    __builtin_amdgcn_s_setprio(0);
    __builtin_amdgcn_s_barrier();

    // ---- phase 2: (msh1, nsh1) ----
    rdA(buf, 1);
    __builtin_amdgcn_s_barrier();
    asm volatile("s_waitcnt lgkmcnt(0)" ::: "memory");
    __builtin_amdgcn_sched_barrier(0);
    __builtin_amdgcn_s_setprio(1);
    MM16(4, b1, 2);
    __builtin_amdgcn_s_setprio(0);
    __builtin_amdgcn_s_barrier();

    // ---- phase 3: (msh1, nsh0); stage A(j+2) quarters {1,3}; boundary vmcnt --
    rdB(buf, 0, b0);
    if (j + 2 < 16) stageA(j + 2, 1);
    __builtin_amdgcn_s_barrier();
    asm volatile("s_waitcnt lgkmcnt(0)" ::: "memory");
    __builtin_amdgcn_sched_barrier(0);
    __builtin_amdgcn_s_setprio(1);
    MM16(4, b0, 0);
    __builtin_amdgcn_s_setprio(0);
    if (j <= 13) {
      asm volatile("s_waitcnt vmcnt(4)" ::: "memory");  // next tile complete
    } else if (j == 14) {
      asm volatile("s_waitcnt vmcnt(0)" ::: "memory");  // tail drain
    }
    __builtin_amdgcn_sched_barrier(0);
    __builtin_amdgcn_s_barrier();
  }
  __syncthreads();

  // Epilogue: 4 chunks of 64 rows staged in LDS -> full-line float4 stores
  float* Cs = (float*)smem;  // 64*260*4 = 66560 B
  const int er = tid >> 3;
  const int ecg = tid & 7;
  float4 bias[8];
  #pragma unroll
  for (int u = 0; u < 8; ++u)
    bias[u] = *(const float4*)&beff[C + ecg * 32 + u * 4];
  #pragma unroll
  for (int c = 0; c < 4; ++c) {
    if (wm == (c >> 1)) {
      #pragma unroll
      for (int m = 0; m < 4; ++m)
        #pragma unroll
        for (int ni = 0; ni < 4; ++ni)
          #pragma unroll
          for (int reg = 0; reg < 4; ++reg)
            Cs[(m * 16 + fkg * 4 + reg) * 260 + wn * 64 + ni * 16 + frow] =
                acc[(c & 1) * 4 + m][ni][reg];
    }
    __syncthreads();
    #pragma unroll
    for (int u = 0; u < 8; ++u) {
      float4 v = *(const float4*)&Cs[er * 260 + ecg * 32 + u * 4];
      v.x += bias[u].x; v.y += bias[u].y; v.z += bias[u].z; v.w += bias[u].w;
      *(float4*)(Out + (size_t)(R + c * 64 + er) * 1024 + C + ecg * 32 + u * 4) = v;
    }
    __syncthreads();
  }
}

// ---------------- Fallback GEMM (reg-staged, f32 X) if ws is small -----------
#define LDSS 72
#define CSTRF 136
__global__ __launch_bounds__(256, 2) void gemm_fb(
    const float* __restrict__ X, const unsigned short* __restrict__ Weff,
    const float* __restrict__ beff, float* __restrict__ Out) {
  __shared__ __align__(16) unsigned short As0[128 * LDSS];
  __shared__ __align__(16) unsigned short As1[128 * LDSS];
  __shared__ __align__(16) unsigned short Bs0[128 * LDSS];
  __shared__ __align__(16) unsigned short Bs1[128 * LDSS];
  const int wg = blockIdx.x;
  const int swz = (wg & 7) * 256 + (wg >> 3);
  const int R = (swz >> 3) * 128;
  const int C = (swz & 7) * 128;
  const int tid = threadIdx.x;
  const int lane = tid & 63;
  const int wave = tid >> 6;
  const int wm = wave >> 1, wn = wave & 1;
  const int frow = lane & 15, fkg = lane >> 4;
  f32x4 acc[4][4];
  #pragma unroll
  for (int mi = 0; mi < 4; ++mi)
    #pragma unroll
    for (int ni = 0; ni < 4; ++ni) acc[mi][ni] = (f32x4){0.f, 0.f, 0.f, 0.f};
  const int ar = tid >> 4, akc = (tid & 15) << 2;
  const int bn_ = tid >> 3, bkc = (tid & 7) << 3;
  const float* Xbase = X + (size_t)(R + ar) * 1024 + akc;
  const unsigned short* Wbase = Weff + (size_t)(C + bn_) * 1024 + bkc;
  float4 av[8];
  uint4 bv[4];
  auto loadTile = [&](int kt) {
    const int kb = kt * 64;
    #pragma unroll
    for (int i = 0; i < 8; ++i) av[i] = *(const float4*)(Xbase + (size_t)i * 16 * 1024 + kb);
    #pragma unroll
    for (int i = 0; i < 4; ++i) bv[i] = *(const uint4*)(Wbase + (size_t)i * 32 * 1024 + kb);
  };
  auto writeTile = [&](unsigned short* Asn, unsigned short* Bsn) {
    #pragma unroll
    for (int i = 0; i < 8; ++i) {
      unsigned short tmp[4] = {f32_to_bf16_rtn(av[i].x), f32_to_bf16_rtn(av[i].y),
                               f32_to_bf16_rtn(av[i].z), f32_to_bf16_rtn(av[i].w)};
      *(uint2*)&Asn[(ar + i * 16) * LDSS + akc] = *(const uint2*)tmp;
    }
    #pragma unroll
    for (int i = 0; i < 4; ++i) *(uint4*)&Bsn[(bn_ + i * 32) * LDSS + bkc] = bv[i];
  };
  loadTile(0);
  writeTile(As0, Bs0);
  __syncthreads();
  unsigned short* Asc = As0; unsigned short* Asn = As1;
  unsigned short* Bsc = Bs0; unsigned short* Bsn = Bs1;
  for (int kt = 0; kt < 16; ++kt) {
    if (kt < 15) loadTile(kt + 1);
    short8 afr[4][2], bfr[4][2];
    #pragma unroll
    for (int mi = 0; mi < 4; ++mi)
      #pragma unroll
      for (int kk = 0; kk < 2; ++kk)
        afr[mi][kk] = *(const short8*)&Asc[(wm * 64 + mi * 16 + frow) * LDSS + kk * 32 + fkg * 8];
    #pragma unroll
    for (int ni = 0; ni < 4; ++ni)
      #pragma unroll
      for (int kk = 0; kk < 2; ++kk)
        bfr[ni][kk] = *(const short8*)&Bsc[(wn * 64 + ni * 16 + frow) * LDSS + kk * 32 + fkg * 8];
    #pragma unroll
    for (int mi = 0; mi < 4; ++mi)
      #pragma unroll
      for (int ni = 0; ni < 4; ++ni)
        #pragma unroll
        for (int kk = 0; kk < 2; ++kk)
          acc[mi][ni] = __builtin_amdgcn_mfma_f32_16x16x32_bf16(
              afr[mi][kk], bfr[ni][kk], acc[mi][ni], 0, 0, 0);
    if (kt < 15) writeTile(Asn, Bsn);
    __syncthreads();
    unsigned short* t1 = Asc; Asc = Asn; Asn = t1;
    unsigned short* t2 = Bsc; Bsc = Bsn; Bsn = t2;
  }
  float* Cs = (float*)As0;
  const int c4 = (tid & 31) << 2;
  float4 bb = *(const float4*)&beff[C + c4];
  #pragma unroll
  for (int mi = 0; mi < 4; ++mi) {
    #pragma unroll
    for (int ni = 0; ni < 4; ++ni) {
      int col = wn * 64 + ni * 16 + frow;
      #pragma unroll
      for (int reg = 0; reg < 4; ++reg)
        Cs[(wm * 16 + fkg * 4 + reg) * CSTRF + col] = acc[mi][ni][reg];
    }
    __syncthreads();
    #pragma unroll
    for (int it = 0; it < 4; ++it) {
      int rloc = it * 8 + (tid >> 5);
      float4 v = *(const float4*)&Cs[rloc * CSTRF + c4];
      v.x += bb.x; v.y += bb.y; v.z += bb.z; v.w += bb.w;
      int grow = R + (rloc >> 4) * 64 + mi * 16 + (rloc & 15);
      *(float4*)(Out + (size_t)grow * 1024 + C + c4) = v;
    }
    __syncthreads();
  }
}

extern "C" void kernel_launch(void* const* d_in, const int* in_sizes, int n_in,
                              void* d_out, int out_size, void* d_ws, size_t ws_size,
                              hipStream_t stream) {
  const float* x = (const float*)d_in[0];
  const float* t = (const float*)d_in[1];
  const float* W = (const float*)d_in[2];
  const float* b = (const float*)d_in[3];
  const float* A = (const float*)d_in[4];
  float* out = (float*)d_out;

  char* ws = (char*)d_ws;
  unsigned short* Weff = (unsigned short*)ws;                 // 2 MB @ 0
  float* beff = (float*)(ws + (2 << 20));                     // 4 KB @ 2 MB
  unsigned short* Xb = (unsigned short*)(ws + (4ull << 20));  // 64 MB @ 4 MB

  const size_t need = (4ull << 20) + (64ull << 20);
  weff_kernel<<<256, 256, 0, stream>>>(A, t, W, b, Weff, beff);
  if (ws_size >= need) {
    convert_x_kernel<<<2048, 256, 0, stream>>>(x, Xb, 33554432 / 8);
    gemm256_kernel<<<512, 512, 0, stream>>>(Xb, Weff, beff, out);
  } else {
    gemm_fb<<<2048, 256, 0, stream>>>(x, Weff, beff, out);
  }
}